// Round 4
// baseline (959.407 us; speedup 1.0000x reference)
//
#include <hip/hip_runtime.h>
#include <hip/hip_bf16.h>
#include <stdint.h>

#define NG 128
#define EPSI 1e-5f

typedef __attribute__((ext_vector_type(8))) __bf16 bf16x8;
typedef __attribute__((ext_vector_type(4))) float f32x4;

union ABFrag { bf16x8 v; unsigned short u[8]; uint4 q; };
union U8 { uint4 q; unsigned short u[8]; };

__device__ __forceinline__ float b2f(unsigned short u){
  union { unsigned int i; float f; } v; v.i = ((unsigned int)u) << 16; return v.f;
}
__device__ __forceinline__ unsigned short f2b(float f){
  union { float f; unsigned int i; } v; v.f = f;
  unsigned int r = v.i + 0x7fffu + ((v.i >> 16) & 1u);
  return (unsigned short)(r >> 16);
}

// ---------------- prep: bf16 conversions (frag order), graph hist, node hist ----------------
__global__ void kprep(const float* __restrict__ emb, const float* __restrict__ W1,
                      const float* __restrict__ W2,
                      const int* __restrict__ ei, const int* __restrict__ batch,
                      unsigned short* __restrict__ embb, unsigned short* __restrict__ WcF,
                      unsigned short* __restrict__ W2F, unsigned int* __restrict__ hist,
                      unsigned int* __restrict__ nodeh, int N, int E){
  __shared__ unsigned int h[NG];
  for (int i = threadIdx.x; i < NG; i += 256) h[i] = 0;
  __syncthreads();
  int idx = blockIdx.x * 256 + threadIdx.x;
  int stride = gridDim.x * 256;
  int embCnt4 = N * 16;  // float4 groups
  for (int i = idx; i < embCnt4; i += stride){
    float4 v = *(const float4*)(emb + (size_t)i * 4);
    ushort4 o; o.x = f2b(v.x); o.y = f2b(v.y); o.z = f2b(v.z); o.w = f2b(v.w);
    *(ushort4*)(embb + (size_t)i * 4) = o;
  }
  for (int i = idx; i < 32 * 2 * 64 * 8; i += stride){
    int j = i & 7, lane = (i >> 3) & 63, ks = (i >> 9) & 1, tn = i >> 10;
    int quad = lane >> 4, l15 = lane & 15;
    int k = ks * 32 + quad * 8 + j;
    int n = tn * 16 + l15;
    float wv = (n < 256) ? W1[k * 256 + n] : W1[(k + 64) * 256 + (n - 256)];
    WcF[i] = f2b(wv);
  }
  for (int i = idx; i < 4 * 8 * 64 * 8; i += stride){
    int j = i & 7, lane = (i >> 3) & 63, ks = (i >> 9) & 7, w = i >> 12;
    int quad = lane >> 4, l15 = lane & 15;
    W2F[i] = f2b(W2[(ks * 32 + quad * 8 + j) * 64 + w * 16 + l15]);
  }
  for (int e = idx; e < E; e += stride){
    int cn = ei[e];
    atomicAdd(&h[batch[cn]], 1u);
    atomicAdd(&nodeh[cn], 1u);
  }
  __syncthreads();
  for (int i = threadIdx.x; i < NG; i += 256)
    if (h[i]) atomicAdd(&hist[i], h[i]);
}

// ---------------- exclusive scan over node histogram (single block) ----------------
__global__ void kscan(const unsigned int* __restrict__ nodeh, unsigned int* __restrict__ ncursor,
                      int N){
  __shared__ unsigned int ts[1024];
  int t = threadIdx.x;
  int chunk = (N + 1023) / 1024;
  int a = t * chunk, b = min(N, a + chunk);
  unsigned int s = 0;
  for (int i = a; i < b; ++i) s += nodeh[i];
  ts[t] = s;
  __syncthreads();
  if (t == 0){
    unsigned int run = 0;
    for (int i = 0; i < 1024; ++i){ unsigned int v = ts[i]; ts[i] = run; run += v; }
  }
  __syncthreads();
  unsigned int base = ts[t];
  for (int i = a; i < b; ++i){ ncursor[i] = base; base += nodeh[i]; }
}

// einfo[p] = {col_node, row_node, graph, orig_edge}, p sorted by col node (=> by graph)
__global__ void kscatter(const int* __restrict__ ei, const int* __restrict__ batch, int E,
                         unsigned int* __restrict__ ncursor, int4* __restrict__ einfo){
  int idx = blockIdx.x * 256 + threadIdx.x;
  for (int e = idx; e < E; e += gridDim.x * 256){
    int cn = ei[e], rn = ei[E + e];
    int g = batch[cn];
    unsigned int p = atomicAdd(&ncursor[cn], 1u);
    einfo[p] = make_int4(cn, rn, g, e);
  }
}

// ---------------- GEMM1: PQ[N,512] = embb[N,64] @ W1cat[64,512] (+b1 on P cols) ----------------
__global__ void __launch_bounds__(256) kgemm1(const unsigned short* __restrict__ embb,
    const unsigned short* __restrict__ WcF, const float* __restrict__ b1,
    unsigned short* __restrict__ PQb, int Nn){
  int wave = threadIdx.x >> 6, lane = threadIdx.x & 63;
  int quad = lane >> 4, l15 = lane & 15;
  int t = blockIdx.x * 4 + wave;
  int tmmax = (Nn + 15) >> 4;
  int tm = t >> 5, tn = t & 31;
  if (tm >= tmmax) return;
  int m = tm * 16 + l15; if (m >= Nn) m = Nn - 1;
  f32x4 acc = {0.f, 0.f, 0.f, 0.f};
  #pragma unroll
  for (int ks = 0; ks < 2; ++ks){
    ABFrag a, b;
    a.q = *(const uint4*)(embb + (size_t)m * 64 + ks * 32 + quad * 8);
    b.q = *(const uint4*)(WcF + ((size_t)(tn * 2 + ks) * 64 + lane) * 8);
    acc = __builtin_amdgcn_mfma_f32_16x16x32_bf16(a.v, b.v, acc, 0, 0, 0);
  }
  int col = tn * 16 + l15;
  float bias = (col < 256) ? b1[col] : 0.0f;
  #pragma unroll
  for (int r = 0; r < 4; ++r){
    int rowg = tm * 16 + quad * 4 + r;
    if (rowg < Nn) PQb[(size_t)rowg * 512 + col] = f2b(acc[r] + bias);
  }
}

// ------- stats over y1 = P[col]+Q[row]; col-sorted edges; 16B loads, 2 edges/wave-step -------
__global__ void kstats1(const unsigned short* __restrict__ PQb, const int4* __restrict__ einfo,
                        int E, float* __restrict__ sum1, float* __restrict__ sq1){
  int wave = threadIdx.x >> 6, lane = threadIdx.x & 63;
  int eo = lane >> 5;         // which edge of the pair
  int c8 = (lane & 31) * 8;   // 8-channel slice
  int per = (E + gridDim.x - 1) / gridDim.x;
  int i0 = blockIdx.x * per;
  int i1 = min(E, i0 + per);
  float s[8], q[8];
  #pragma unroll
  for (int t = 0; t < 8; ++t){ s[t] = 0.f; q[t] = 0.f; }
  int cur = -1;
  for (int base = i0 + wave * 2; base < i1; base += 32){
    int4 ev[4];
    #pragma unroll
    for (int k = 0; k < 4; ++k){
      int p = base + k * 8 + eo;
      ev[k] = (p < i1) ? einfo[p] : make_int4(0, 0, -1, 0);
    }
    U8 pu[4], qu[4];
    #pragma unroll
    for (int k = 0; k < 4; ++k){
      pu[k].q = *(const uint4*)(PQb + (size_t)ev[k].x * 512 + c8);
      qu[k].q = *(const uint4*)(PQb + (size_t)ev[k].y * 512 + 256 + c8);
    }
    #pragma unroll
    for (int k = 0; k < 4; ++k){
      int g = ev[k].z;
      if (g >= 0){
        if (g != cur){
          if (cur >= 0){
            #pragma unroll
            for (int t = 0; t < 8; ++t){
              atomicAdd(&sum1[cur * 256 + c8 + t], s[t]);
              atomicAdd(&sq1[cur * 256 + c8 + t], q[t]);
              s[t] = 0.f; q[t] = 0.f;
            }
          }
          cur = g;
        }
        #pragma unroll
        for (int t = 0; t < 8; ++t){
          float y = b2f(pu[k].u[t]) + b2f(qu[k].u[t]);
          s[t] += y; q[t] += y * y;
        }
      }
    }
  }
  if (cur >= 0){
    #pragma unroll
    for (int t = 0; t < 8; ++t){
      atomicAdd(&sum1[cur * 256 + c8 + t], s[t]);
      atomicAdd(&sq1[cur * 256 + c8 + t], q[t]);
    }
  }
}

__global__ void kfin(const float* __restrict__ sum, const float* __restrict__ sq,
                     const unsigned int* __restrict__ hist,
                     float* __restrict__ meanA, float* __restrict__ rstdA, int C){
  int i = blockIdx.x * blockDim.x + threadIdx.x;
  if (i >= NG * C) return;
  int g = i / C;
  float cnt = fmaxf((float)hist[g], 1.0f);
  float m = sum[i] / cnt;
  float v = sq[i] / cnt - m * m;
  meanA[i] = m;
  rstdA[i] = rsqrtf(fmaxf(v, 0.f) + EPSI);
}

// ------- fused: norm+ReLU L1 -> GEMM2 -> y2 (64-edge tiles, 16B gathers, clean epilogue) -----
__global__ void __launch_bounds__(256) kmain(const unsigned short* __restrict__ PQb,
    const unsigned short* __restrict__ W2F, const int4* __restrict__ einfo,
    const float* __restrict__ mean1, const float* __restrict__ rstd1,
    const float* __restrict__ b2, unsigned short* __restrict__ y2b, int E){
  __shared__ unsigned short tileA[64][264];  // stride 264: 2-way LDS aliasing only (free)
  int wave = threadIdx.x >> 6, lane = threadIdx.x & 63;
  int quad = lane >> 4, l15 = lane & 15;
  int eo = lane >> 5;         // pair slot for stage-1
  int c8 = (lane & 31) * 8;   // 8-channel slice for stage-1
  ABFrag bk[8];
  #pragma unroll
  for (int ks = 0; ks < 8; ++ks)
    bk[ks].q = *(const uint4*)(W2F + ((size_t)(wave * 8 + ks) * 64 + lane) * 8);
  int cc = wave * 16 + l15;
  float bias2 = b2[cc];
  int nt = (E + 63) >> 6;
  for (int tb = blockIdx.x; tb < nt; tb += gridDim.x){
    int p0 = tb * 64;
    __syncthreads();
    if (p0 + 64 <= E){
      #pragma unroll
      for (int j = 0; j < 8; ++j){
        int le = wave * 16 + j * 2 + eo;
        int4 ev = einfo[p0 + le];
        U8 pu, qu, hv;
        pu.q = *(const uint4*)(PQb + (size_t)ev.x * 512 + c8);
        qu.q = *(const uint4*)(PQb + (size_t)ev.y * 512 + 256 + c8);
        const float* mg = mean1 + ev.z * 256 + c8;
        const float* rg = rstd1 + ev.z * 256 + c8;
        float4 m0 = *(const float4*)mg, m1 = *(const float4*)(mg + 4);
        float4 r0 = *(const float4*)rg, r1 = *(const float4*)(rg + 4);
        hv.u[0] = f2b(fmaxf(0.f, (b2f(pu.u[0]) + b2f(qu.u[0]) - m0.x) * r0.x));
        hv.u[1] = f2b(fmaxf(0.f, (b2f(pu.u[1]) + b2f(qu.u[1]) - m0.y) * r0.y));
        hv.u[2] = f2b(fmaxf(0.f, (b2f(pu.u[2]) + b2f(qu.u[2]) - m0.z) * r0.z));
        hv.u[3] = f2b(fmaxf(0.f, (b2f(pu.u[3]) + b2f(qu.u[3]) - m0.w) * r0.w));
        hv.u[4] = f2b(fmaxf(0.f, (b2f(pu.u[4]) + b2f(qu.u[4]) - m1.x) * r1.x));
        hv.u[5] = f2b(fmaxf(0.f, (b2f(pu.u[5]) + b2f(qu.u[5]) - m1.y) * r1.y));
        hv.u[6] = f2b(fmaxf(0.f, (b2f(pu.u[6]) + b2f(qu.u[6]) - m1.z) * r1.z));
        hv.u[7] = f2b(fmaxf(0.f, (b2f(pu.u[7]) + b2f(qu.u[7]) - m1.w) * r1.w));
        *(uint4*)&tileA[le][c8] = hv.q;
      }
    } else {
      #pragma unroll
      for (int j = 0; j < 8; ++j){
        int le = wave * 16 + j * 2 + eo;
        int p = p0 + le;
        U8 hv; hv.q = make_uint4(0, 0, 0, 0);
        if (p < E){
          int4 ev = einfo[p];
          U8 pu, qu;
          pu.q = *(const uint4*)(PQb + (size_t)ev.x * 512 + c8);
          qu.q = *(const uint4*)(PQb + (size_t)ev.y * 512 + 256 + c8);
          const float* mg = mean1 + ev.z * 256 + c8;
          const float* rg = rstd1 + ev.z * 256 + c8;
          float4 m0 = *(const float4*)mg, m1 = *(const float4*)(mg + 4);
          float4 r0 = *(const float4*)rg, r1 = *(const float4*)(rg + 4);
          hv.u[0] = f2b(fmaxf(0.f, (b2f(pu.u[0]) + b2f(qu.u[0]) - m0.x) * r0.x));
          hv.u[1] = f2b(fmaxf(0.f, (b2f(pu.u[1]) + b2f(qu.u[1]) - m0.y) * r0.y));
          hv.u[2] = f2b(fmaxf(0.f, (b2f(pu.u[2]) + b2f(qu.u[2]) - m0.z) * r0.z));
          hv.u[3] = f2b(fmaxf(0.f, (b2f(pu.u[3]) + b2f(qu.u[3]) - m0.w) * r0.w));
          hv.u[4] = f2b(fmaxf(0.f, (b2f(pu.u[4]) + b2f(qu.u[4]) - m1.x) * r1.x));
          hv.u[5] = f2b(fmaxf(0.f, (b2f(pu.u[5]) + b2f(qu.u[5]) - m1.y) * r1.y));
          hv.u[6] = f2b(fmaxf(0.f, (b2f(pu.u[6]) + b2f(qu.u[6]) - m1.z) * r1.z));
          hv.u[7] = f2b(fmaxf(0.f, (b2f(pu.u[7]) + b2f(qu.u[7]) - m1.w) * r1.w));
        }
        *(uint4*)&tileA[le][c8] = hv.q;
      }
    }
    __syncthreads();
    f32x4 acc[4];
    #pragma unroll
    for (int eg = 0; eg < 4; ++eg){ acc[eg][0]=0.f; acc[eg][1]=0.f; acc[eg][2]=0.f; acc[eg][3]=0.f; }
    #pragma unroll
    for (int eg = 0; eg < 4; ++eg)
      #pragma unroll
      for (int ks = 0; ks < 8; ++ks){
        ABFrag a;
        a.q = *(const uint4*)&tileA[eg * 16 + l15][ks * 32 + quad * 8];
        acc[eg] = __builtin_amdgcn_mfma_f32_16x16x32_bf16(a.v, bk[ks].v, acc[eg], 0, 0, 0);
      }
    #pragma unroll
    for (int eg = 0; eg < 4; ++eg)
      #pragma unroll
      for (int r = 0; r < 4; ++r){
        int p = p0 + eg * 16 + quad * 4 + r;
        if (p < E) y2b[(size_t)p * 64 + cc] = f2b(acc[eg][r] + bias2);
      }
  }
}

// ---------------- stats over y2 (sorted, contiguous, 16B loads, 8 edges/wave-step) ----------
__global__ void kstats2(const unsigned short* __restrict__ y2b, const int4* __restrict__ einfo,
                        int E, float* __restrict__ sum2, float* __restrict__ sq2){
  int wave = threadIdx.x >> 6, lane = threadIdx.x & 63;
  int eo = lane >> 3;        // edge slot in octet
  int c8 = (lane & 7) * 8;   // channel slice
  int per = (E + gridDim.x - 1) / gridDim.x;
  int i0 = blockIdx.x * per, i1 = min(E, i0 + per);
  float s[8], q[8];
  #pragma unroll
  for (int t = 0; t < 8; ++t){ s[t] = 0.f; q[t] = 0.f; }
  int cur = -1;
  for (int base = i0 + wave * 8; base < i1; base += 32){
    int p = base + eo;
    int g = -1;
    U8 yv;
    if (p < i1){
      g = einfo[p].z;
      yv.q = *(const uint4*)(y2b + (size_t)p * 64 + c8);
    }
    if (g >= 0){
      if (g != cur){
        if (cur >= 0){
          #pragma unroll
          for (int t = 0; t < 8; ++t){
            atomicAdd(&sum2[cur * 64 + c8 + t], s[t]);
            atomicAdd(&sq2[cur * 64 + c8 + t], q[t]);
            s[t] = 0.f; q[t] = 0.f;
          }
        }
        cur = g;
      }
      #pragma unroll
      for (int t = 0; t < 8; ++t){
        float y = b2f(yv.u[t]);
        s[t] += y; q[t] += y * y;
      }
    }
  }
  if (cur >= 0){
    #pragma unroll
    for (int t = 0; t < 8; ++t){
      atomicAdd(&sum2[cur * 64 + c8 + t], s[t]);
      atomicAdd(&sq2[cur * 64 + c8 + t], q[t]);
    }
  }
}

// ------- final: norm+ReLU L2 -> GEMV W3 -> scatter; 8 lanes per edge + shuffle reduce -------
__global__ void kfinal(const unsigned short* __restrict__ y2b, const int4* __restrict__ einfo,
                       const float* __restrict__ mean2, const float* __restrict__ rstd2,
                       const float* __restrict__ W3, const float* __restrict__ b3,
                       float* __restrict__ out, int E){
  int sub = threadIdx.x & 7;
  int c8 = sub * 8;
  float w3r[8];
  #pragma unroll
  for (int t = 0; t < 8; ++t) w3r[t] = W3[c8 + t];
  float b3v = b3[0];
  int step = (gridDim.x * blockDim.x) >> 3;
  for (int i = (blockIdx.x * blockDim.x + threadIdx.x) >> 3; i < E; i += step){
    int4 ev = einfo[i];
    U8 yv; yv.q = *(const uint4*)(y2b + (size_t)i * 64 + c8);
    const float* mg = mean2 + ev.z * 64 + c8;
    const float* rg = rstd2 + ev.z * 64 + c8;
    float4 m0 = *(const float4*)mg, m1 = *(const float4*)(mg + 4);
    float4 r0 = *(const float4*)rg, r1 = *(const float4*)(rg + 4);
    float a = 0.f;
    a += fmaxf(0.f, (b2f(yv.u[0]) - m0.x) * r0.x) * w3r[0];
    a += fmaxf(0.f, (b2f(yv.u[1]) - m0.y) * r0.y) * w3r[1];
    a += fmaxf(0.f, (b2f(yv.u[2]) - m0.z) * r0.z) * w3r[2];
    a += fmaxf(0.f, (b2f(yv.u[3]) - m0.w) * r0.w) * w3r[3];
    a += fmaxf(0.f, (b2f(yv.u[4]) - m1.x) * r1.x) * w3r[4];
    a += fmaxf(0.f, (b2f(yv.u[5]) - m1.y) * r1.y) * w3r[5];
    a += fmaxf(0.f, (b2f(yv.u[6]) - m1.z) * r1.z) * w3r[6];
    a += fmaxf(0.f, (b2f(yv.u[7]) - m1.w) * r1.w) * w3r[7];
    a += __shfl_xor(a, 1);
    a += __shfl_xor(a, 2);
    a += __shfl_xor(a, 4);
    if (sub == 0) out[ev.w] = a + b3v;
  }
}

extern "C" void kernel_launch(void* const* d_in, const int* in_sizes, int n_in,
                              void* d_out, int out_size, void* d_ws, size_t ws_size,
                              hipStream_t stream){
  const float* emb  = (const float*)d_in[0];
  const int*   ei   = (const int*)d_in[1];
  const int*   batch= (const int*)d_in[2];
  const float* W1   = (const float*)d_in[3];
  const float* b1   = (const float*)d_in[4];
  const float* W2   = (const float*)d_in[5];
  const float* b2   = (const float*)d_in[6];
  const float* W3   = (const float*)d_in[7];
  const float* b3   = (const float*)d_in[8];
  int N = in_sizes[0] / 64;
  int E = in_sizes[1] / 2;
  float* out = (float*)d_out;

  char* w = (char*)d_ws;
  size_t off = 0;
  auto nxt = [&](size_t bytes) -> char* {
    char* p = w + off;
    off = (off + bytes + 255) & ~(size_t)255;
    return p;
  };
  unsigned short* embb = (unsigned short*)nxt((size_t)N * 64 * 2);
  unsigned short* WcF  = (unsigned short*)nxt(32 * 2 * 64 * 8 * 2);
  unsigned short* W2F  = (unsigned short*)nxt(4 * 8 * 64 * 8 * 2);
  unsigned short* PQb  = (unsigned short*)nxt((size_t)N * 512 * 2);
  unsigned short* y2b  = (unsigned short*)nxt((size_t)E * 64 * 2);
  int4* einfo = (int4*)nxt((size_t)E * 16);
  float* mean1 = (float*)nxt(NG * 256 * 4);
  float* rstd1 = (float*)nxt(NG * 256 * 4);
  float* mean2 = (float*)nxt(NG * 64 * 4);
  float* rstd2 = (float*)nxt(NG * 64 * 4);
  unsigned int* ncursor = (unsigned int*)nxt((size_t)N * 4);
  // zero-init region (contiguous, one memset)
  char* zbase = w + off;
  unsigned int* hist  = (unsigned int*)nxt(NG * 4);
  unsigned int* nodeh = (unsigned int*)nxt((size_t)N * 4);
  float* sum1 = (float*)nxt(NG * 256 * 4);
  float* sq1  = (float*)nxt(NG * 256 * 4);
  float* sum2 = (float*)nxt(NG * 64 * 4);
  float* sq2  = (float*)nxt(NG * 64 * 4);
  size_t zbytes = (size_t)((w + off) - zbase);
  hipMemsetAsync(zbase, 0, zbytes, stream);

  kprep<<<2048, 256, 0, stream>>>(emb, W1, W2, ei, batch, embb, WcF, W2F, hist, nodeh, N, E);
  kscan<<<1, 1024, 0, stream>>>(nodeh, ncursor, N);
  kscatter<<<2048, 256, 0, stream>>>(ei, batch, E, ncursor, einfo);
  {
    int tiles = ((N + 15) / 16) * 32;
    kgemm1<<<(tiles + 3) / 4, 256, 0, stream>>>(embb, WcF, b1, PQb, N);
  }
  kstats1<<<1024, 256, 0, stream>>>(PQb, einfo, E, sum1, sq1);
  kfin<<<(NG * 256 + 255) / 256, 256, 0, stream>>>(sum1, sq1, hist, mean1, rstd1, 256);
  kmain<<<2048, 256, 0, stream>>>(PQb, W2F, einfo, mean1, rstd1, b2, y2b, E);
  kstats2<<<1024, 256, 0, stream>>>(y2b, einfo, E, sum2, sq2);
  kfin<<<(NG * 64 + 255) / 256, 256, 0, stream>>>(sum2, sq2, hist, mean2, rstd2, 64);
  kfinal<<<2048, 256, 0, stream>>>(y2b, einfo, mean2, rstd2, W3, b3, out, E);
}

// Round 5
// 633.499 us; speedup vs baseline: 1.5145x; 1.5145x over previous
//
#include <hip/hip_runtime.h>
#include <hip/hip_bf16.h>
#include <stdint.h>

#define NG 128
#define EPSI 1e-5f

typedef __attribute__((ext_vector_type(8))) __bf16 bf16x8;
typedef __attribute__((ext_vector_type(4))) float f32x4;

union ABFrag { bf16x8 v; unsigned short u[8]; uint4 q; };
union U8 { uint4 q; unsigned short u[8]; };

__device__ __forceinline__ float b2f(unsigned short u){
  union { unsigned int i; float f; } v; v.i = ((unsigned int)u) << 16; return v.f;
}
__device__ __forceinline__ unsigned short f2b(float f){
  union { float f; unsigned int i; } v; v.f = f;
  unsigned int r = v.i + 0x7fffu + ((v.i >> 16) & 1u);
  return (unsigned short)(r >> 16);
}

// ---------------- prep: bf16 conversions (frag order), graph hist, node hist ----------------
__global__ void kprep(const float* __restrict__ emb, const float* __restrict__ W1,
                      const float* __restrict__ W2,
                      const int* __restrict__ ei, const int* __restrict__ batch,
                      unsigned short* __restrict__ embb, unsigned short* __restrict__ WcF,
                      unsigned short* __restrict__ W2F, unsigned int* __restrict__ hist,
                      unsigned int* __restrict__ nodeh, int N, int E){
  __shared__ unsigned int h[NG];
  for (int i = threadIdx.x; i < NG; i += 256) h[i] = 0;
  __syncthreads();
  int idx = blockIdx.x * 256 + threadIdx.x;
  int stride = gridDim.x * 256;
  int embCnt4 = N * 16;  // float4 groups
  for (int i = idx; i < embCnt4; i += stride){
    float4 v = *(const float4*)(emb + (size_t)i * 4);
    ushort4 o; o.x = f2b(v.x); o.y = f2b(v.y); o.z = f2b(v.z); o.w = f2b(v.w);
    *(ushort4*)(embb + (size_t)i * 4) = o;
  }
  for (int i = idx; i < 32 * 2 * 64 * 8; i += stride){
    int j = i & 7, lane = (i >> 3) & 63, ks = (i >> 9) & 1, tn = i >> 10;
    int quad = lane >> 4, l15 = lane & 15;
    int k = ks * 32 + quad * 8 + j;
    int n = tn * 16 + l15;
    float wv = (n < 256) ? W1[k * 256 + n] : W1[(k + 64) * 256 + (n - 256)];
    WcF[i] = f2b(wv);
  }
  for (int i = idx; i < 4 * 8 * 64 * 8; i += stride){
    int j = i & 7, lane = (i >> 3) & 63, ks = (i >> 9) & 7, w = i >> 12;
    int quad = lane >> 4, l15 = lane & 15;
    W2F[i] = f2b(W2[(ks * 32 + quad * 8 + j) * 64 + w * 16 + l15]);
  }
  for (int e = idx; e < E; e += stride){
    int cn = ei[e];
    atomicAdd(&h[batch[cn]], 1u);
    atomicAdd(&nodeh[cn], 1u);
  }
  __syncthreads();
  for (int i = threadIdx.x; i < NG; i += 256)
    if (h[i]) atomicAdd(&hist[i], h[i]);
}

// ---------------- exclusive scan over node histogram (single block) ----------------
__global__ void kscan(const unsigned int* __restrict__ nodeh, unsigned int* __restrict__ ncursor,
                      int N){
  __shared__ unsigned int ts[1024];
  int t = threadIdx.x;
  int chunk = (N + 1023) / 1024;
  int a = t * chunk, b = min(N, a + chunk);
  unsigned int s = 0;
  for (int i = a; i < b; ++i) s += nodeh[i];
  ts[t] = s;
  __syncthreads();
  if (t == 0){
    unsigned int run = 0;
    for (int i = 0; i < 1024; ++i){ unsigned int v = ts[i]; ts[i] = run; run += v; }
  }
  __syncthreads();
  unsigned int base = ts[t];
  for (int i = a; i < b; ++i){ ncursor[i] = base; base += nodeh[i]; }
}

// einfo[p] = {col_node, row_node, graph, orig_edge}, p sorted by col node (=> by graph)
__global__ void kscatter(const int* __restrict__ ei, const int* __restrict__ batch, int E,
                         unsigned int* __restrict__ ncursor, int4* __restrict__ einfo){
  int idx = blockIdx.x * 256 + threadIdx.x;
  for (int e = idx; e < E; e += gridDim.x * 256){
    int cn = ei[e], rn = ei[E + e];
    int g = batch[cn];
    unsigned int p = atomicAdd(&ncursor[cn], 1u);
    einfo[p] = make_int4(cn, rn, g, e);
  }
}

// ---------------- GEMM1: PQ[N,512] = embb[N,64] @ W1cat[64,512] (+b1 on P cols) ----------------
__global__ void __launch_bounds__(256) kgemm1(const unsigned short* __restrict__ embb,
    const unsigned short* __restrict__ WcF, const float* __restrict__ b1,
    unsigned short* __restrict__ PQb, int Nn){
  int wave = threadIdx.x >> 6, lane = threadIdx.x & 63;
  int quad = lane >> 4, l15 = lane & 15;
  int t = blockIdx.x * 4 + wave;
  int tmmax = (Nn + 15) >> 4;
  int tm = t >> 5, tn = t & 31;
  if (tm >= tmmax) return;
  int m = tm * 16 + l15; if (m >= Nn) m = Nn - 1;
  f32x4 acc = {0.f, 0.f, 0.f, 0.f};
  #pragma unroll
  for (int ks = 0; ks < 2; ++ks){
    ABFrag a, b;
    a.q = *(const uint4*)(embb + (size_t)m * 64 + ks * 32 + quad * 8);
    b.q = *(const uint4*)(WcF + ((size_t)(tn * 2 + ks) * 64 + lane) * 8);
    acc = __builtin_amdgcn_mfma_f32_16x16x32_bf16(a.v, b.v, acc, 0, 0, 0);
  }
  int col = tn * 16 + l15;
  float bias = (col < 256) ? b1[col] : 0.0f;
  #pragma unroll
  for (int r = 0; r < 4; ++r){
    int rowg = tm * 16 + quad * 4 + r;
    if (rowg < Nn) PQb[(size_t)rowg * 512 + col] = f2b(acc[r] + bias);
  }
}

// ------- stats over y1 = P[col]+Q[row]; contiguous 512-edge chunk/block, LDS accumulate -----
__global__ void __launch_bounds__(256) kstats1(const unsigned short* __restrict__ PQb,
                        const int4* __restrict__ einfo,
                        int E, float* __restrict__ sum1, float* __restrict__ sq1){
  __shared__ float lsum[8][256];
  __shared__ float lsq[8][256];
  int tid = threadIdx.x;
  for (int i = tid; i < 8 * 256; i += 256){ ((float*)lsum)[i] = 0.f; ((float*)lsq)[i] = 0.f; }
  __syncthreads();
  int i0 = blockIdx.x * 512;
  int i1 = min(E, i0 + 512);
  int gfirst = einfo[i0].z;
  int eo = tid >> 5;          // 8 edge slots
  int c8 = (tid & 31) * 8;    // 8-channel slice
  float s[8], q[8];
  #pragma unroll
  for (int t = 0; t < 8; ++t){ s[t] = 0.f; q[t] = 0.f; }
  int cur = -1;
  auto flushreg = [&](){
    if (cur >= 0){
      unsigned slot = (unsigned)(cur - gfirst);
      if (slot < 8u){
        #pragma unroll
        for (int t = 0; t < 8; ++t){
          atomicAdd(&lsum[slot][c8 + t], s[t]);
          atomicAdd(&lsq[slot][c8 + t], q[t]);
        }
      } else {
        #pragma unroll
        for (int t = 0; t < 8; ++t){
          atomicAdd(&sum1[cur * 256 + c8 + t], s[t]);
          atomicAdd(&sq1[cur * 256 + c8 + t], q[t]);
        }
      }
      #pragma unroll
      for (int t = 0; t < 8; ++t){ s[t] = 0.f; q[t] = 0.f; }
    }
  };
  for (int p = i0 + eo; p < i1; p += 16){
    int4 ev0 = einfo[p];
    int p2 = p + 8;
    int4 ev1 = (p2 < i1) ? einfo[p2] : make_int4(0, 0, -1, 0);
    U8 pu0, qu0, pu1, qu1;
    pu0.q = *(const uint4*)(PQb + (size_t)ev0.x * 512 + c8);
    qu0.q = *(const uint4*)(PQb + (size_t)ev0.y * 512 + 256 + c8);
    pu1.q = *(const uint4*)(PQb + (size_t)ev1.x * 512 + c8);
    qu1.q = *(const uint4*)(PQb + (size_t)ev1.y * 512 + 256 + c8);
    if (ev0.z != cur){ flushreg(); cur = ev0.z; }
    #pragma unroll
    for (int t = 0; t < 8; ++t){
      float y = b2f(pu0.u[t]) + b2f(qu0.u[t]);
      s[t] += y; q[t] += y * y;
    }
    if (ev1.z >= 0){
      if (ev1.z != cur){ flushreg(); cur = ev1.z; }
      #pragma unroll
      for (int t = 0; t < 8; ++t){
        float y = b2f(pu1.u[t]) + b2f(qu1.u[t]);
        s[t] += y; q[t] += y * y;
      }
    }
  }
  flushreg();
  __syncthreads();
  for (int i = tid; i < 8 * 256; i += 256){
    int slot = i >> 8, ch = i & 255;
    float vs = lsum[slot][ch], vq = lsq[slot][ch];
    if (vs != 0.f || vq != 0.f){
      int g = gfirst + slot;
      atomicAdd(&sum1[g * 256 + ch], vs);
      atomicAdd(&sq1[g * 256 + ch], vq);
    }
  }
}

__global__ void kfin(const float* __restrict__ sum, const float* __restrict__ sq,
                     const unsigned int* __restrict__ hist,
                     float* __restrict__ meanA, float* __restrict__ rstdA, int C){
  int i = blockIdx.x * blockDim.x + threadIdx.x;
  if (i >= NG * C) return;
  int g = i / C;
  float cnt = fmaxf((float)hist[g], 1.0f);
  float m = sum[i] / cnt;
  float v = sq[i] / cnt - m * m;
  meanA[i] = m;
  rstdA[i] = rsqrtf(fmaxf(v, 0.f) + EPSI);
}

// ------- fused: norm+ReLU L1 -> GEMM2 -> y2 (64-edge tiles, 16B gathers, clean epilogue) -----
__global__ void __launch_bounds__(256) kmain(const unsigned short* __restrict__ PQb,
    const unsigned short* __restrict__ W2F, const int4* __restrict__ einfo,
    const float* __restrict__ mean1, const float* __restrict__ rstd1,
    const float* __restrict__ b2, unsigned short* __restrict__ y2b, int E){
  __shared__ unsigned short tileA[64][264];  // stride 264: 2-way LDS aliasing only (free)
  int wave = threadIdx.x >> 6, lane = threadIdx.x & 63;
  int quad = lane >> 4, l15 = lane & 15;
  int eo = lane >> 5;         // pair slot for stage-1
  int c8 = (lane & 31) * 8;   // 8-channel slice for stage-1
  ABFrag bk[8];
  #pragma unroll
  for (int ks = 0; ks < 8; ++ks)
    bk[ks].q = *(const uint4*)(W2F + ((size_t)(wave * 8 + ks) * 64 + lane) * 8);
  int cc = wave * 16 + l15;
  float bias2 = b2[cc];
  int nt = (E + 63) >> 6;
  for (int tb = blockIdx.x; tb < nt; tb += gridDim.x){
    int p0 = tb * 64;
    __syncthreads();
    if (p0 + 64 <= E){
      #pragma unroll
      for (int j = 0; j < 8; ++j){
        int le = wave * 16 + j * 2 + eo;
        int4 ev = einfo[p0 + le];
        U8 pu, qu, hv;
        pu.q = *(const uint4*)(PQb + (size_t)ev.x * 512 + c8);
        qu.q = *(const uint4*)(PQb + (size_t)ev.y * 512 + 256 + c8);
        const float* mg = mean1 + ev.z * 256 + c8;
        const float* rg = rstd1 + ev.z * 256 + c8;
        float4 m0 = *(const float4*)mg, m1 = *(const float4*)(mg + 4);
        float4 r0 = *(const float4*)rg, r1 = *(const float4*)(rg + 4);
        hv.u[0] = f2b(fmaxf(0.f, (b2f(pu.u[0]) + b2f(qu.u[0]) - m0.x) * r0.x));
        hv.u[1] = f2b(fmaxf(0.f, (b2f(pu.u[1]) + b2f(qu.u[1]) - m0.y) * r0.y));
        hv.u[2] = f2b(fmaxf(0.f, (b2f(pu.u[2]) + b2f(qu.u[2]) - m0.z) * r0.z));
        hv.u[3] = f2b(fmaxf(0.f, (b2f(pu.u[3]) + b2f(qu.u[3]) - m0.w) * r0.w));
        hv.u[4] = f2b(fmaxf(0.f, (b2f(pu.u[4]) + b2f(qu.u[4]) - m1.x) * r1.x));
        hv.u[5] = f2b(fmaxf(0.f, (b2f(pu.u[5]) + b2f(qu.u[5]) - m1.y) * r1.y));
        hv.u[6] = f2b(fmaxf(0.f, (b2f(pu.u[6]) + b2f(qu.u[6]) - m1.z) * r1.z));
        hv.u[7] = f2b(fmaxf(0.f, (b2f(pu.u[7]) + b2f(qu.u[7]) - m1.w) * r1.w));
        *(uint4*)&tileA[le][c8] = hv.q;
      }
    } else {
      #pragma unroll
      for (int j = 0; j < 8; ++j){
        int le = wave * 16 + j * 2 + eo;
        int p = p0 + le;
        U8 hv; hv.q = make_uint4(0, 0, 0, 0);
        if (p < E){
          int4 ev = einfo[p];
          U8 pu, qu;
          pu.q = *(const uint4*)(PQb + (size_t)ev.x * 512 + c8);
          qu.q = *(const uint4*)(PQb + (size_t)ev.y * 512 + 256 + c8);
          const float* mg = mean1 + ev.z * 256 + c8;
          const float* rg = rstd1 + ev.z * 256 + c8;
          float4 m0 = *(const float4*)mg, m1 = *(const float4*)(mg + 4);
          float4 r0 = *(const float4*)rg, r1 = *(const float4*)(rg + 4);
          hv.u[0] = f2b(fmaxf(0.f, (b2f(pu.u[0]) + b2f(qu.u[0]) - m0.x) * r0.x));
          hv.u[1] = f2b(fmaxf(0.f, (b2f(pu.u[1]) + b2f(qu.u[1]) - m0.y) * r0.y));
          hv.u[2] = f2b(fmaxf(0.f, (b2f(pu.u[2]) + b2f(qu.u[2]) - m0.z) * r0.z));
          hv.u[3] = f2b(fmaxf(0.f, (b2f(pu.u[3]) + b2f(qu.u[3]) - m0.w) * r0.w));
          hv.u[4] = f2b(fmaxf(0.f, (b2f(pu.u[4]) + b2f(qu.u[4]) - m1.x) * r1.x));
          hv.u[5] = f2b(fmaxf(0.f, (b2f(pu.u[5]) + b2f(qu.u[5]) - m1.y) * r1.y));
          hv.u[6] = f2b(fmaxf(0.f, (b2f(pu.u[6]) + b2f(qu.u[6]) - m1.z) * r1.z));
          hv.u[7] = f2b(fmaxf(0.f, (b2f(pu.u[7]) + b2f(qu.u[7]) - m1.w) * r1.w));
        }
        *(uint4*)&tileA[le][c8] = hv.q;
      }
    }
    __syncthreads();
    f32x4 acc[4];
    #pragma unroll
    for (int eg = 0; eg < 4; ++eg){ acc[eg][0]=0.f; acc[eg][1]=0.f; acc[eg][2]=0.f; acc[eg][3]=0.f; }
    #pragma unroll
    for (int eg = 0; eg < 4; ++eg)
      #pragma unroll
      for (int ks = 0; ks < 8; ++ks){
        ABFrag a;
        a.q = *(const uint4*)&tileA[eg * 16 + l15][ks * 32 + quad * 8];
        acc[eg] = __builtin_amdgcn_mfma_f32_16x16x32_bf16(a.v, bk[ks].v, acc[eg], 0, 0, 0);
      }
    #pragma unroll
    for (int eg = 0; eg < 4; ++eg)
      #pragma unroll
      for (int r = 0; r < 4; ++r){
        int p = p0 + eg * 16 + quad * 4 + r;
        if (p < E) y2b[(size_t)p * 64 + cc] = f2b(acc[eg][r] + bias2);
      }
  }
}

// ------- stats over y2; contiguous 1024-edge chunk/block, LDS accumulate -------
__global__ void __launch_bounds__(256) kstats2(const unsigned short* __restrict__ y2b,
                        const int4* __restrict__ einfo,
                        int E, float* __restrict__ sum2, float* __restrict__ sq2){
  __shared__ float lsum[8][64];
  __shared__ float lsq[8][64];
  int tid = threadIdx.x;
  for (int i = tid; i < 8 * 64; i += 256){ ((float*)lsum)[i] = 0.f; ((float*)lsq)[i] = 0.f; }
  __syncthreads();
  int i0 = blockIdx.x * 1024;
  int i1 = min(E, i0 + 1024);
  int gfirst = einfo[i0].z;
  int eo = tid >> 3;         // 32 edge slots
  int c8 = (tid & 7) * 8;    // 8-channel slice
  float s[8], q[8];
  #pragma unroll
  for (int t = 0; t < 8; ++t){ s[t] = 0.f; q[t] = 0.f; }
  int cur = -1;
  auto flushreg = [&](){
    if (cur >= 0){
      unsigned slot = (unsigned)(cur - gfirst);
      if (slot < 8u){
        #pragma unroll
        for (int t = 0; t < 8; ++t){
          atomicAdd(&lsum[slot][c8 + t], s[t]);
          atomicAdd(&lsq[slot][c8 + t], q[t]);
        }
      } else {
        #pragma unroll
        for (int t = 0; t < 8; ++t){
          atomicAdd(&sum2[cur * 64 + c8 + t], s[t]);
          atomicAdd(&sq2[cur * 64 + c8 + t], q[t]);
        }
      }
      #pragma unroll
      for (int t = 0; t < 8; ++t){ s[t] = 0.f; q[t] = 0.f; }
    }
  };
  for (int p = i0 + eo; p < i1; p += 64){
    int g0 = einfo[p].z;
    int p2 = p + 32;
    int g1 = (p2 < i1) ? einfo[p2].z : -1;
    U8 y0, y1;
    y0.q = *(const uint4*)(y2b + (size_t)p * 64 + c8);
    y1.q = (g1 >= 0) ? *(const uint4*)(y2b + (size_t)p2 * 64 + c8) : make_uint4(0,0,0,0);
    if (g0 != cur){ flushreg(); cur = g0; }
    #pragma unroll
    for (int t = 0; t < 8; ++t){
      float y = b2f(y0.u[t]);
      s[t] += y; q[t] += y * y;
    }
    if (g1 >= 0){
      if (g1 != cur){ flushreg(); cur = g1; }
      #pragma unroll
      for (int t = 0; t < 8; ++t){
        float y = b2f(y1.u[t]);
        s[t] += y; q[t] += y * y;
      }
    }
  }
  flushreg();
  __syncthreads();
  for (int i = tid; i < 8 * 64; i += 256){
    int slot = i >> 6, ch = i & 63;
    float vs = lsum[slot][ch], vq = lsq[slot][ch];
    if (vs != 0.f || vq != 0.f){
      int g = gfirst + slot;
      atomicAdd(&sum2[g * 64 + ch], vs);
      atomicAdd(&sq2[g * 64 + ch], vq);
    }
  }
}

// ------- final: norm+ReLU L2 -> GEMV W3 -> scatter; 8 lanes per edge + shuffle reduce -------
__global__ void kfinal(const unsigned short* __restrict__ y2b, const int4* __restrict__ einfo,
                       const float* __restrict__ mean2, const float* __restrict__ rstd2,
                       const float* __restrict__ W3, const float* __restrict__ b3,
                       float* __restrict__ out, int E){
  int sub = threadIdx.x & 7;
  int c8 = sub * 8;
  float w3r[8];
  #pragma unroll
  for (int t = 0; t < 8; ++t) w3r[t] = W3[c8 + t];
  float b3v = b3[0];
  int step = (gridDim.x * blockDim.x) >> 3;
  for (int i = (blockIdx.x * blockDim.x + threadIdx.x) >> 3; i < E; i += step){
    int4 ev = einfo[i];
    U8 yv; yv.q = *(const uint4*)(y2b + (size_t)i * 64 + c8);
    const float* mg = mean2 + ev.z * 64 + c8;
    const float* rg = rstd2 + ev.z * 64 + c8;
    float4 m0 = *(const float4*)mg, m1 = *(const float4*)(mg + 4);
    float4 r0 = *(const float4*)rg, r1 = *(const float4*)(rg + 4);
    float a = 0.f;
    a += fmaxf(0.f, (b2f(yv.u[0]) - m0.x) * r0.x) * w3r[0];
    a += fmaxf(0.f, (b2f(yv.u[1]) - m0.y) * r0.y) * w3r[1];
    a += fmaxf(0.f, (b2f(yv.u[2]) - m0.z) * r0.z) * w3r[2];
    a += fmaxf(0.f, (b2f(yv.u[3]) - m0.w) * r0.w) * w3r[3];
    a += fmaxf(0.f, (b2f(yv.u[4]) - m1.x) * r1.x) * w3r[4];
    a += fmaxf(0.f, (b2f(yv.u[5]) - m1.y) * r1.y) * w3r[5];
    a += fmaxf(0.f, (b2f(yv.u[6]) - m1.z) * r1.z) * w3r[6];
    a += fmaxf(0.f, (b2f(yv.u[7]) - m1.w) * r1.w) * w3r[7];
    a += __shfl_xor(a, 1);
    a += __shfl_xor(a, 2);
    a += __shfl_xor(a, 4);
    if (sub == 0) out[ev.w] = a + b3v;
  }
}

extern "C" void kernel_launch(void* const* d_in, const int* in_sizes, int n_in,
                              void* d_out, int out_size, void* d_ws, size_t ws_size,
                              hipStream_t stream){
  const float* emb  = (const float*)d_in[0];
  const int*   ei   = (const int*)d_in[1];
  const int*   batch= (const int*)d_in[2];
  const float* W1   = (const float*)d_in[3];
  const float* b1   = (const float*)d_in[4];
  const float* W2   = (const float*)d_in[5];
  const float* b2   = (const float*)d_in[6];
  const float* W3   = (const float*)d_in[7];
  const float* b3   = (const float*)d_in[8];
  int N = in_sizes[0] / 64;
  int E = in_sizes[1] / 2;
  float* out = (float*)d_out;

  char* w = (char*)d_ws;
  size_t off = 0;
  auto nxt = [&](size_t bytes) -> char* {
    char* p = w + off;
    off = (off + bytes + 255) & ~(size_t)255;
    return p;
  };
  unsigned short* embb = (unsigned short*)nxt((size_t)N * 64 * 2);
  unsigned short* WcF  = (unsigned short*)nxt(32 * 2 * 64 * 8 * 2);
  unsigned short* W2F  = (unsigned short*)nxt(4 * 8 * 64 * 8 * 2);
  unsigned short* PQb  = (unsigned short*)nxt((size_t)N * 512 * 2);
  unsigned short* y2b  = (unsigned short*)nxt((size_t)E * 64 * 2);
  int4* einfo = (int4*)nxt((size_t)E * 16);
  float* mean1 = (float*)nxt(NG * 256 * 4);
  float* rstd1 = (float*)nxt(NG * 256 * 4);
  float* mean2 = (float*)nxt(NG * 64 * 4);
  float* rstd2 = (float*)nxt(NG * 64 * 4);
  unsigned int* ncursor = (unsigned int*)nxt((size_t)N * 4);
  // zero-init region (contiguous, one memset)
  char* zbase = w + off;
  unsigned int* hist  = (unsigned int*)nxt(NG * 4);
  unsigned int* nodeh = (unsigned int*)nxt((size_t)N * 4);
  float* sum1 = (float*)nxt(NG * 256 * 4);
  float* sq1  = (float*)nxt(NG * 256 * 4);
  float* sum2 = (float*)nxt(NG * 64 * 4);
  float* sq2  = (float*)nxt(NG * 64 * 4);
  size_t zbytes = (size_t)((w + off) - zbase);
  hipMemsetAsync(zbase, 0, zbytes, stream);

  kprep<<<2048, 256, 0, stream>>>(emb, W1, W2, ei, batch, embb, WcF, W2F, hist, nodeh, N, E);
  kscan<<<1, 1024, 0, stream>>>(nodeh, ncursor, N);
  kscatter<<<2048, 256, 0, stream>>>(ei, batch, E, ncursor, einfo);
  {
    int tiles = ((N + 15) / 16) * 32;
    kgemm1<<<(tiles + 3) / 4, 256, 0, stream>>>(embb, WcF, b1, PQb, N);
  }
  kstats1<<<(E + 511) / 512, 256, 0, stream>>>(PQb, einfo, E, sum1, sq1);
  kfin<<<(NG * 256 + 255) / 256, 256, 0, stream>>>(sum1, sq1, hist, mean1, rstd1, 256);
  kmain<<<2048, 256, 0, stream>>>(PQb, W2F, einfo, mean1, rstd1, b2, y2b, E);
  kstats2<<<(E + 1023) / 1024, 256, 0, stream>>>(y2b, einfo, E, sum2, sq2);
  kfin<<<(NG * 64 + 255) / 256, 256, 0, stream>>>(sum2, sq2, hist, mean2, rstd2, 64);
  kfinal<<<2048, 256, 0, stream>>>(y2b, einfo, mean2, rstd2, W3, b3, out, E);
}